// Round 15
// baseline (36.002 us; speedup 1.0000x reference)
//
#include <hip/hip_runtime.h>

// CTC batch cost (Keras ctc_batch_cost), B=256, T=512, C=128, L=64.
// 256 blocks x 128 threads: wave0 = consumer (recurrence), wave1 = producer.
// Same step math as r14 (blank-normalized linear domain, 0.5/step decay in ql,
// per-lane pow2 exponent, trigger renorm). New chunk pipeline:
//  - ql stored TRANSPOSED: ql[buf][r*64+lane] -> all ds reads/writes at bank
//    lane%32 (2-way, conflict-free), b32 with imm offsets.
//  - triple-buffered ql, quad-buffered raw: producer stages chunk i+4 and
//    produces chunk i+2 during interval i (load-to-use = 2 intervals > HBM
//    latency -> vmcnt stall ~0).
//  - consumer prefetches chunk c+1's ql into registers DURING compute of
//    chunk c (qA/qB register double-buffer, 2x-unrolled loop, no moves).

#define B_ 256
#define T_ 512
#define C_ 128
#define L_ 64
#define BLANK_ 127
#define EPSF (1e-7f)
#define CHUNK 32
#define LN2F 0.6931471805599453f

#define EXP2(x) __builtin_amdgcn_exp2f(x)   // v_exp_f32 (base-2)
#define LOG2(x) __builtin_amdgcn_logf(x)    // v_log_f32 (base-2)

__device__ __forceinline__ float lse2_2(float a, float b) {
    float m = fmaxf(a, b);
    float d = fminf(a, b) - m;
    return m + LOG2(1.0f + EXP2(d));
}

__device__ __forceinline__ float dppf(float x) {  // lane i <- i-1; lane0 <- 0
    return __int_as_float(__builtin_amdgcn_update_dpp(
        0, __float_as_int(x), 0x138, 0xf, 0xf, false));
}
__device__ __forceinline__ int dppi(int x) {
    return __builtin_amdgcn_update_dpp(0, x, 0x138, 0xf, 0xf, false);
}

__device__ __forceinline__ void stage_chunk(const float* gsrc, float* ldst, int lane) {
#pragma unroll
    for (int i = 0; i < CHUNK / 2; ++i) {
        __builtin_amdgcn_global_load_lds(
            (const __attribute__((address_space(1))) void*)(gsrc + i * 256 + lane * 4),
            (__attribute__((address_space(3))) void*)(ldst + i * 256),
            16, 0, 0);
    }
}

__device__ __forceinline__ void produce_chunk(const float* __restrict__ rk,
        float* __restrict__ qd, int lane, int label, int t0, int tend, float& llg)
{
    const float pbv = rk[(lane & 31) * C_ + BLANK_] + EPSF;
    const float rpb = 0.5f / pbv;             // 0.5 = uniform per-step decay
    const int t = t0 + lane;
    const bool lgv = (lane < 32) && (t >= 1) && (t < tend);
    llg += lgv ? LOG2(pbv) : 0.0f;
    float* qb = qd + lane;                    // writes at bank lane%32 (free)
#pragma unroll
    for (int r = 0; r < CHUNK; ++r) {
        const float pl = rk[r * C_ + label] + EPSF;
        const float rb = __int_as_float(
            __builtin_amdgcn_readlane(__float_as_int(rpb), r));
        qb[r * 64] = pl * rb;                 // 0.5*(pl+eps)/(pb+eps)
    }
}

// trigger test + rare renorm block (wave-uniform branch)
template<bool HAS128>
__device__ __forceinline__ void maybe_renorm(float& A0, float& A1, float& A2,
                                             int& e, float& sch, float& kq,
                                             float skipf2) {
    float m2 = fmaxf(A0, A1);
    if (HAS128) m2 = fmaxf(m2, A2);
    const bool out = (m2 > 16777216.0f) ||
                     ((m2 < 5.9604644775390625e-8f) && (m2 > 0.0f));  // 2^+-24
    if (__any(out)) {
        const float mm = (m2 == 0.0f) ? 1.0f : m2;
        const int eb = __float_as_int(mm) >> 23;           // biased exp
        const float s = __int_as_float((254 - eb) << 23);  // exact 2^(127-eb)
        A0 *= s; A1 *= s;
        if (HAS128) A2 *= s;
        e += eb - 127;
        const int ep = dppi(e);
        int d = ep - e;
        d = d < -125 ? -125 : d;
        d = d > 127 ? 127 : d;
        sch = __int_as_float((d + 126) << 23);             // 0.5*2^d
        kq = skipf2 * sch;
    }
}

template<bool HAS128>
__device__ __forceinline__ void step(float& A0, float& A1, float& A2,
                                     float sch, float kq, float ql) {
    const float s1 = dppf(A1);                // cross-lane: A1 of lane-1
    const float Y  = A1 + A0;                 // runs parallel with dpp
    const float A2n = HAS128 ? (A2 + A1) * 0.5f : A2;
    const float P1 = s1 * sch;
    const float A1n = fmaf(kq, s1, Y) * ql;   // chain: dpp -> fma -> mul
    const float A0n = fmaf(A0, 0.5f, P1);
    A0 = A0n; A1 = A1n;
    if (HAS128) A2 = A2n;
}

template<bool HAS128>
struct Consumer {
    const float (*qlb)[CHUNK * 64];
    const float* extra;
    int lane, lab, tend, nmax, b;
    float* out;
    float A0, A1, A2, sch, kq, skipf2;
    int e;

    __device__ __forceinline__ void loadq(int c, float* arr) {
        const float* qb = &qlb[c % 3][lane];
#pragma unroll
        for (int r = 0; r < CHUNK; ++r) arr[r] = qb[r * 64];  // bank lane%32
    }

    __device__ __forceinline__ void iter(int c, float* cur, float* nxt) {
        if (c + 1 < nmax) loadq(c + 1, nxt);      // overlap with compute below
        __builtin_amdgcn_sched_barrier(0);
        const int rem = tend - c * CHUNK;
        if (c == 0) {
            A0 = (lane == 0) ? extra[1] : 0.0f;   // t=0 init (raw, no decay)
            A1 = (lane == 0) ? extra[0] : 0.0f;
#pragma unroll
            for (int u = 1; u < 32; ++u) {
                step<HAS128>(A0, A1, A2, sch, kq, cur[u]);
                if ((u & 3) == 3)
                    maybe_renorm<HAS128>(A0, A1, A2, e, sch, kq, skipf2);
            }
        } else if (rem >= CHUNK) {
#pragma unroll
            for (int u = 0; u < 32; ++u) {
                step<HAS128>(A0, A1, A2, sch, kq, cur[u]);
                if ((u & 3) == 3)
                    maybe_renorm<HAS128>(A0, A1, A2, e, sch, kq, skipf2);
            }
        } else {
            for (int u = 0; u < rem; ++u) {       // short tail, once
                step<HAS128>(A0, A1, A2, sch, kq, cur[u]);
                if ((u & 3) == 3)
                    maybe_renorm<HAS128>(A0, A1, A2, e, sch, kq, skipf2);
            }
        }
        asm volatile("s_waitcnt lgkmcnt(0)" ::: "memory");
        __builtin_amdgcn_s_barrier();
    }

    __device__ __forceinline__ void run() {
        float qA[CHUNK], qB[CHUNK];
        loadq(0, qA);                             // chunk0 ready since P0
        int c = 0;
        for (;;) {
            iter(c, qA, qB); if (++c >= nmax) break;
            iter(c, qB, qA); if (++c >= nmax) break;
        }
        __builtin_amdgcn_s_barrier();             // BF: lg ready
        const float lg = extra[2];
        const float ef = (float)e + lg + (float)(tend - 1);
        const float l0 = LOG2(A0) + ef;
        const float l1 = LOG2(A1) + ef;
        const float a_prev = __shfl(l1, lab - 1);            // state 2*lab-1
        float a_last;
        if (HAS128) {
            const float l2 = LOG2(A2) + ef;
            a_last = __shfl(l2, 63);                         // state 128
        } else {
            a_last = __shfl(l0, lab);                        // state 2*lab
        }
        if (lane == 0) out[b] = -LN2F * lse2_2(a_last, a_prev);
    }
};

__global__ __launch_bounds__(128) void ctc_fwd_kernel(
    const int* __restrict__ y_true, const float* __restrict__ y_pred,
    const int* __restrict__ input_len, const int* __restrict__ label_len,
    float* __restrict__ out)
{
    __shared__ __align__(16) float raw[4][CHUNK * C_];     // 64 KB
    __shared__ __align__(16) float qlb[3][CHUNK * 64];     // 24 KB
    __shared__ float extra[4];                             // A1init, A0init, lg

    const int b = blockIdx.x;
    const int tid = threadIdx.x;
    const int lane = tid & 63;
    const float* __restrict__ Pg = y_pred + (size_t)b * T_ * C_;
    const int label = y_true[b * L_ + lane];
    const int in_len = input_len[b];
    const int tend = in_len < T_ ? in_len : T_;            // >= 256
    const int nmax = (tend + CHUNK - 1) / CHUNK;           // 8..16

    if (tid >= 64) {
        // ------------------------- producer (wave 1) -------------------------
        float llg = 0.0f;
#pragma unroll
        for (int k = 0; k < 4; ++k)                        // nmax >= 8 > 4
            stage_chunk(Pg + (size_t)k * CHUNK * C_, &raw[k][0], lane);
        asm volatile("s_waitcnt vmcnt(48)" ::: "memory");  // chunk0 landed
        produce_chunk(&raw[0][0], &qlb[0][0], lane, label, 0, tend, llg);
        if (lane == 0) {
            extra[0] = raw[0][label] + EPSF;               // A1 init (s=1)
            extra[1] = raw[0][BLANK_] + EPSF;              // A0 init (s=0)
        }
        asm volatile("s_waitcnt vmcnt(32)" ::: "memory");  // chunk1 landed
        produce_chunk(&raw[1][0], &qlb[1][0], lane, label, CHUNK, tend, llg);
        asm volatile("s_waitcnt lgkmcnt(0)" ::: "memory");
        __builtin_amdgcn_s_barrier();                      // P0
        for (int i = 0; i < nmax; ++i) {
            if (i + 4 < nmax)
                stage_chunk(Pg + (size_t)(i + 4) * CHUNK * C_,
                            &raw[(i + 4) & 3][0], lane);
            if (i + 2 < nmax) {
                // drain through chunk i+2's 16 loads (newer: i+3, i+4 stages)
                if (i + 4 < nmax)
                    asm volatile("s_waitcnt vmcnt(32)" ::: "memory");
                else if (i + 3 < nmax)
                    asm volatile("s_waitcnt vmcnt(16)" ::: "memory");
                else
                    asm volatile("s_waitcnt vmcnt(0)" ::: "memory");
                produce_chunk(&raw[(i + 2) & 3][0], &qlb[(i + 2) % 3][0],
                              lane, label, (i + 2) * CHUNK, tend, llg);
            }
            asm volatile("s_waitcnt lgkmcnt(0)" ::: "memory");
            __builtin_amdgcn_s_barrier();                  // per interval
        }
#pragma unroll
        for (int off = 16; off >= 1; off >>= 1) llg += __shfl_xor(llg, off);
        if (lane == 0) extra[2] = llg;                     // lg
        asm volatile("s_waitcnt lgkmcnt(0)" ::: "memory");
        __builtin_amdgcn_s_barrier();                      // BF
    } else {
        // ------------------------- consumer (wave 0) -------------------------
        const int lprev = __shfl_up(label, 1);
        const float skipf2 = (lane > 0 && label != lprev) ? 2.0f : 0.0f;
        const int lab = label_len[b];
        __builtin_amdgcn_s_barrier();                      // P0
        if (lab == L_) {
            Consumer<true> cns{qlb, extra, lane, lab, tend, nmax, b, out,
                               0.0f, 0.0f, 0.0f, 0.5f, skipf2 * 0.5f, skipf2, 0};
            cns.run();
        } else {
            Consumer<false> cns{qlb, extra, lane, lab, tend, nmax, b, out,
                                0.0f, 0.0f, 0.0f, 0.5f, skipf2 * 0.5f, skipf2, 0};
            cns.run();
        }
    }
}

extern "C" void kernel_launch(void* const* d_in, const int* in_sizes, int n_in,
                              void* d_out, int out_size, void* d_ws, size_t ws_size,
                              hipStream_t stream) {
    const int*   y_true    = (const int*)d_in[0];
    const float* y_pred    = (const float*)d_in[1];
    const int*   input_len = (const int*)d_in[2];
    const int*   label_len = (const int*)d_in[3];
    float* out = (float*)d_out;

    ctc_fwd_kernel<<<B_, 128, 0, stream>>>(y_true, y_pred, input_len, label_len, out);
}

// Round 17
// 35.690 us; speedup vs baseline: 1.0087x; 1.0087x over previous
//
#include <hip/hip_runtime.h>

// CTC batch cost (Keras ctc_batch_cost), B=256, T=512, C=128, L=64.
// 256 blocks x 256 threads: wave0 = consumer (recurrence), waves1-3 = producers.
// Producer wave w owns chunks c == w-1 (mod 3): per interval i (== c-3) it
// stages chunk i+6 (private raw dbuf, per-wave vmcnt, 3-interval load-to-use)
// and produces ql for chunk i+3 into qlb[(i+3)%4] (4 slots -> no collision
// with consumer's read slot). Consumer = r13 step math (blank-normalized
// linear domain, 0.5/step decay in ql, per-lane pow2 exponent, trigger
// renorm), transposed conflict-free b32 ql reads. One s_barrier/interval.

#define B_ 256
#define T_ 512
#define C_ 128
#define L_ 64
#define BLANK_ 127
#define EPSF (1e-7f)
#define CHUNK 32
#define LN2F 0.6931471805599453f

#define EXP2(x) __builtin_amdgcn_exp2f(x)   // v_exp_f32 (base-2)
#define LOG2(x) __builtin_amdgcn_logf(x)    // v_log_f32 (base-2)

__device__ __forceinline__ float lse2_2(float a, float b) {
    float m = fmaxf(a, b);
    float d = fminf(a, b) - m;
    return m + LOG2(1.0f + EXP2(d));
}

__device__ __forceinline__ float dppf(float x) {  // lane i <- i-1; lane0 <- 0
    return __int_as_float(__builtin_amdgcn_update_dpp(
        0, __float_as_int(x), 0x138, 0xf, 0xf, false));
}
__device__ __forceinline__ int dppi(int x) {
    return __builtin_amdgcn_update_dpp(0, x, 0x138, 0xf, 0xf, false);
}

__device__ __forceinline__ void stage_chunk(const float* gsrc, float* ldst, int lane) {
#pragma unroll
    for (int i = 0; i < CHUNK / 2; ++i) {
        __builtin_amdgcn_global_load_lds(
            (const __attribute__((address_space(1))) void*)(gsrc + i * 256 + lane * 4),
            (__attribute__((address_space(3))) void*)(ldst + i * 256),
            16, 0, 0);
    }
}

__device__ __forceinline__ void produce_chunk(const float* __restrict__ rk,
        float* __restrict__ qd, int lane, int label, int t0, int tend, float& llg)
{
    const float pbv = rk[(lane & 31) * C_ + BLANK_] + EPSF;
    const float rpb = 0.5f / pbv;             // 0.5 = uniform per-step decay
    const int t = t0 + lane;
    const bool lgv = (lane < 32) && (t >= 1) && (t < tend);
    llg += lgv ? LOG2(pbv) : 0.0f;
    float* qb = qd + lane;                    // bank lane%32: conflict-free
#pragma unroll
    for (int r = 0; r < CHUNK; ++r) {
        const float pl = rk[r * C_ + label] + EPSF;
        const float rb = __int_as_float(
            __builtin_amdgcn_readlane(__float_as_int(rpb), r));
        qb[r * 64] = pl * rb;                 // 0.5*(pl+eps)/(pb+eps)
    }
}

// trigger test + rare renorm block (wave-uniform branch)
template<bool HAS128>
__device__ __forceinline__ void maybe_renorm(float& A0, float& A1, float& A2,
                                             int& e, float& sch, float& kq,
                                             float skipf2) {
    float m2 = fmaxf(A0, A1);
    if (HAS128) m2 = fmaxf(m2, A2);
    const bool out = (m2 > 16777216.0f) ||
                     ((m2 < 5.9604644775390625e-8f) && (m2 > 0.0f));  // 2^+-24
    if (__any(out)) {
        const float mm = (m2 == 0.0f) ? 1.0f : m2;
        const int eb = __float_as_int(mm) >> 23;           // biased exp
        const float s = __int_as_float((254 - eb) << 23);  // exact 2^(127-eb)
        A0 *= s; A1 *= s;
        if (HAS128) A2 *= s;
        e += eb - 127;
        const int ep = dppi(e);
        int d = ep - e;
        d = d < -125 ? -125 : d;
        d = d > 127 ? 127 : d;
        sch = __int_as_float((d + 126) << 23);             // 0.5*2^d
        kq = skipf2 * sch;
    }
}

template<bool HAS128>
__device__ __forceinline__ void step(float& A0, float& A1, float& A2,
                                     float sch, float kq, float ql) {
    const float s1 = dppf(A1);                // cross-lane: A1 of lane-1
    const float Y  = A1 + A0;                 // runs parallel with dpp
    const float A2n = HAS128 ? (A2 + A1) * 0.5f : A2;
    const float P1 = s1 * sch;
    const float A1n = fmaf(kq, s1, Y) * ql;   // chain: dpp -> fma -> mul
    const float A0n = fmaf(A0, 0.5f, P1);
    A0 = A0n; A1 = A1n;
    if (HAS128) A2 = A2n;
}

template<bool HAS128>
__device__ __forceinline__ void consumer_run(const float (*qlb)[CHUNK * 64],
        const float* extra, int lane, int lab, int tend, int nmax,
        float skipf2, float* out, int b)
{
    float A0 = 0.0f, A1 = 0.0f, A2 = 0.0f;
    float sch = 0.5f, kq = skipf2 * 0.5f;
    int e = 0;

    for (int c = 0; c < nmax; ++c) {
        const float* qb = &qlb[c & 3][lane];
        float q[CHUNK];
#pragma unroll
        for (int r = 0; r < CHUNK; ++r) q[r] = qb[r * 64];   // conflict-free
        __builtin_amdgcn_sched_barrier(0);

        const int rem = tend - c * CHUNK;
        if (c == 0) {
            A0 = (lane == 0) ? extra[1] : 0.0f;   // t=0 init (raw, no decay)
            A1 = (lane == 0) ? extra[0] : 0.0f;
#pragma unroll
            for (int u = 1; u < 32; ++u) {
                step<HAS128>(A0, A1, A2, sch, kq, q[u]);
                if ((u & 3) == 3)
                    maybe_renorm<HAS128>(A0, A1, A2, e, sch, kq, skipf2);
            }
        } else if (rem >= CHUNK) {
#pragma unroll
            for (int u = 0; u < 32; ++u) {
                step<HAS128>(A0, A1, A2, sch, kq, q[u]);
                if ((u & 3) == 3)
                    maybe_renorm<HAS128>(A0, A1, A2, e, sch, kq, skipf2);
            }
        } else {
            for (int u = 0; u < rem; ++u) {       // short tail, once
                step<HAS128>(A0, A1, A2, sch, kq, q[u]);
                if ((u & 3) == 3)
                    maybe_renorm<HAS128>(A0, A1, A2, e, sch, kq, skipf2);
            }
        }
        __builtin_amdgcn_s_barrier();             // end of interval c
    }
    __builtin_amdgcn_s_barrier();                 // BF: lg slots ready
    const float lg = extra[2] + extra[3] + extra[4];
    const float ef = (float)e + lg + (float)(tend - 1);   // decay accounting
    const float l0 = LOG2(A0) + ef;
    const float l1 = LOG2(A1) + ef;
    const float a_prev = __shfl(l1, lab - 1);             // state 2*lab-1
    float a_last;
    if (HAS128) {
        const float l2 = LOG2(A2) + ef;
        a_last = __shfl(l2, 63);                          // state 128
    } else {
        a_last = __shfl(l0, lab);                         // state 2*lab
    }
    if (lane == 0) out[b] = -LN2F * lse2_2(a_last, a_prev);
}

__global__ __launch_bounds__(256) void ctc_fwd_kernel(
    const int* __restrict__ y_true, const float* __restrict__ y_pred,
    const int* __restrict__ input_len, const int* __restrict__ label_len,
    float* __restrict__ out)
{
    __shared__ __align__(16) float raw[3][2][CHUNK * C_];  // 96 KB
    __shared__ __align__(16) float qlb[4][CHUNK * 64];     // 32 KB
    __shared__ float extra[8];          // [0]=A1init [1]=A0init [2..4]=llg

    const int b = blockIdx.x;
    const int tid = threadIdx.x;
    const int lane = tid & 63;
    const int wid = tid >> 6;                              // 0=consumer, 1..3
    const float* __restrict__ Pg = y_pred + (size_t)b * T_ * C_;
    const int label = y_true[b * L_ + lane];
    const int in_len = input_len[b];
    const int tend = in_len < T_ ? in_len : T_;            // >= 256
    const int nmax = (tend + CHUNK - 1) / CHUNK;           // 8..16

    if (wid > 0) {
        // --------------------- producer wave (pi = wid-1) ---------------------
        const int pi = wid - 1;
        float llg = 0.0f;
        // pre-loop: stage chunks pi and pi+3 (nmax >= 8 so both exist)
        stage_chunk(Pg + (size_t)pi * CHUNK * C_, &raw[pi][0][0], lane);
        stage_chunk(Pg + (size_t)(pi + 3) * CHUNK * C_, &raw[pi][1][0], lane);
        asm volatile("s_waitcnt vmcnt(16)" ::: "memory");  // chunk pi landed
        produce_chunk(&raw[pi][0][0], &qlb[pi][0], lane, label,
                      pi * CHUNK, tend, llg);
        if (pi == 0 && lane == 0) {
            extra[0] = raw[0][0][label]  + EPSF;           // A1 init (s=1)
            extra[1] = raw[0][0][BLANK_] + EPSF;           // A0 init (s=0)
        }
        asm volatile("s_waitcnt lgkmcnt(0)" ::: "memory");
        __builtin_amdgcn_s_barrier();                      // P0
        for (int i = 0; i < nmax; ++i) {
            if (i % 3 == pi) {                             // my interval
                const int js = i + 6, jp = i + 3;
                if (js < nmax)
                    stage_chunk(Pg + (size_t)js * CHUNK * C_,
                                &raw[pi][(js / 3) & 1][0], lane);
                if (jp < nmax) {
                    if (js < nmax) asm volatile("s_waitcnt vmcnt(16)" ::: "memory");
                    else           asm volatile("s_waitcnt vmcnt(0)" ::: "memory");
                    produce_chunk(&raw[pi][(jp / 3) & 1][0], &qlb[jp & 3][0],
                                  lane, label, jp * CHUNK, tend, llg);
                    asm volatile("s_waitcnt lgkmcnt(0)" ::: "memory");
                }
            }
            __builtin_amdgcn_s_barrier();                  // end of interval i
        }
#pragma unroll
        for (int off = 16; off >= 1; off >>= 1) llg += __shfl_xor(llg, off);
        if (lane == 0) extra[2 + pi] = llg;
        asm volatile("s_waitcnt lgkmcnt(0)" ::: "memory");
        __builtin_amdgcn_s_barrier();                      // BF
    } else {
        // ------------------------- consumer (wave 0) -------------------------
        const int lprev = __shfl_up(label, 1);
        const float skipf2 = (lane > 0 && label != lprev) ? 2.0f : 0.0f;
        const int lab = label_len[b];
        __builtin_amdgcn_s_barrier();                      // P0
        if (lab == L_)
            consumer_run<true >(qlb, extra, lane, lab, tend, nmax, skipf2, out, b);
        else
            consumer_run<false>(qlb, extra, lane, lab, tend, nmax, skipf2, out, b);
    }
}

extern "C" void kernel_launch(void* const* d_in, const int* in_sizes, int n_in,
                              void* d_out, int out_size, void* d_ws, size_t ws_size,
                              hipStream_t stream) {
    const int*   y_true    = (const int*)d_in[0];
    const float* y_pred    = (const float*)d_in[1];
    const int*   input_len = (const int*)d_in[2];
    const int*   label_len = (const int*)d_in[3];
    float* out = (float*)d_out;

    ctc_fwd_kernel<<<B_, 256, 0, stream>>>(y_true, y_pred, input_len, label_len, out);
}

// Round 18
// 25.657 us; speedup vs baseline: 1.4032x; 1.3911x over previous
//
#include <hip/hip_runtime.h>

// CTC batch cost (Keras ctc_batch_cost), B=256, T=512, C=128, L=64.
// 256 blocks x 128 threads: wave0 = consumer (recurrence), wave1 = producer.
// r13 math: blank-normalized linear domain, 0.5/step decay folded into ql,
// per-lane pow2 exponent, trigger renorm every 4 steps (wave-vote, rare).
// Fixes vs r13: (1) NO dynamic register-array indexing (rule: one runtime
// index sends the whole array to scratch) -- tail/first intervals use a
// fully-unrolled GUARDED path with wave-uniform selects; (2) 64-step barrier
// intervals (2 chunks) halve per-interval fixed costs; (3) producer uses
// v_rcp (tolerance 48 >> 1ulp).

#define B_ 256
#define T_ 512
#define C_ 128
#define L_ 64
#define BLANK_ 127
#define EPSF (1e-7f)
#define CHUNK 32
#define ISTEP 64           // steps per barrier interval
#define QSTR 68            // per-lane ql stride (dwords); 272B, 16B-aligned
#define LN2F 0.6931471805599453f

#define EXP2(x) __builtin_amdgcn_exp2f(x)   // v_exp_f32 (base-2)
#define LOG2(x) __builtin_amdgcn_logf(x)    // v_log_f32 (base-2)

__device__ __forceinline__ float lse2_2(float a, float b) {
    float m = fmaxf(a, b);
    float d = fminf(a, b) - m;
    return m + LOG2(1.0f + EXP2(d));
}

__device__ __forceinline__ float dppf(float x) {  // lane i <- i-1; lane0 <- 0
    return __int_as_float(__builtin_amdgcn_update_dpp(
        0, __float_as_int(x), 0x138, 0xf, 0xf, false));
}
__device__ __forceinline__ int dppi(int x) {
    return __builtin_amdgcn_update_dpp(0, x, 0x138, 0xf, 0xf, false);
}

__device__ __forceinline__ void stage_chunk(const float* gsrc, float* ldst, int lane) {
#pragma unroll
    for (int i = 0; i < CHUNK / 2; ++i) {
        __builtin_amdgcn_global_load_lds(
            (const __attribute__((address_space(1))) void*)(gsrc + i * 256 + lane * 4),
            (__attribute__((address_space(3))) void*)(ldst + i * 256),
            16, 0, 0);
    }
}

// one 32-row chunk of ql into qd (= qlb[slot] + lane*QSTR + rowoff)
__device__ __forceinline__ void produce_chunk(const float* __restrict__ rk,
        float* __restrict__ qd, int lane, int label, int t0, int tend, float& llg)
{
    const float pbv = rk[(lane & 31) * C_ + BLANK_] + EPSF;
    const float rpb = __builtin_amdgcn_rcpf(pbv) * 0.5f;  // 0.5 = decay
    const int t = t0 + lane;
    const bool lgv = (lane < 32) && (t >= 1) && (t < tend);
    llg += lgv ? LOG2(pbv) : 0.0f;
#pragma unroll
    for (int k = 0; k < 8; ++k) {
        float q[4];
#pragma unroll
        for (int j = 0; j < 4; ++j) {
            const int r = 4 * k + j;
            const float pl = rk[r * C_ + label] + EPSF;
            const float rb = __int_as_float(
                __builtin_amdgcn_readlane(__float_as_int(rpb), r));
            q[j] = pl * rb;                   // 0.5*(pl+eps)/(pb+eps)
        }
        *reinterpret_cast<float4*>(qd + 4 * k) =
            make_float4(q[0], q[1], q[2], q[3]);
    }
}

// trigger test + rare renorm block (wave-uniform branch)
template<bool HAS128>
__device__ __forceinline__ void maybe_renorm(float& A0, float& A1, float& A2,
                                             int& e, float& sch, float& kq,
                                             float skipf2) {
    float m2 = fmaxf(A0, A1);
    if (HAS128) m2 = fmaxf(m2, A2);
    const bool out = (m2 > 16777216.0f) ||
                     ((m2 < 5.9604644775390625e-8f) && (m2 > 0.0f));  // 2^+-24
    if (__any(out)) {
        const float mm = (m2 == 0.0f) ? 1.0f : m2;
        const int eb = __float_as_int(mm) >> 23;           // biased exp
        const float s = __int_as_float((254 - eb) << 23);  // exact 2^(127-eb)
        A0 *= s; A1 *= s;
        if (HAS128) A2 *= s;
        e += eb - 127;
        const int ep = dppi(e);
        int d = ep - e;
        d = d < -125 ? -125 : d;
        d = d > 127 ? 127 : d;
        sch = __int_as_float((d + 126) << 23);             // 0.5*2^d
        kq = skipf2 * sch;
    }
}

template<bool HAS128>
__device__ __forceinline__ void step(float& A0, float& A1, float& A2,
                                     float sch, float kq, float ql) {
    const float s1 = dppf(A1);                // cross-lane: A1 of lane-1
    const float Y  = A1 + A0;                 // runs parallel with dpp
    const float A2n = HAS128 ? (A2 + A1) * 0.5f : A2;
    const float P1 = s1 * sch;
    const float A1n = fmaf(kq, s1, Y) * ql;   // chain: dpp -> fma -> mul
    const float A0n = fmaf(A0, 0.5f, P1);
    A0 = A0n; A1 = A1n;
    if (HAS128) A2 = A2n;
}

template<bool HAS128>
__device__ __forceinline__ void consumer_run(const float (*qlb)[64 * QSTR],
        const float* extra, int lane, int lab, int tend, int nI,
        float skipf2, float* out, int b)
{
    float A0 = 0.0f, A1 = 0.0f, A2 = 0.0f;
    float sch = 0.5f, kq = skipf2 * 0.5f;
    int e = 0;

    for (int c = 0; c < nI; ++c) {
        const float* qb = &qlb[c & 1][lane * QSTR];
        float q[ISTEP];
#pragma unroll
        for (int k = 0; k < ISTEP / 4; ++k) {
            const float4 t4 = *reinterpret_cast<const float4*>(qb + 4 * k);
            q[4*k+0] = t4.x; q[4*k+1] = t4.y;
            q[4*k+2] = t4.z; q[4*k+3] = t4.w;
        }
        __builtin_amdgcn_sched_barrier(0);

        const int rem = tend - c * ISTEP;
        if (c == 0) {
            A0 = (lane == 0) ? extra[1] : 0.0f;   // t=0 init (raw, no decay)
            A1 = (lane == 0) ? extra[0] : 0.0f;
#pragma unroll
            for (int u = 1; u < ISTEP; ++u) {     // static indices only
                step<HAS128>(A0, A1, A2, sch, kq, q[u]);
                if ((u & 3) == 3)
                    maybe_renorm<HAS128>(A0, A1, A2, e, sch, kq, skipf2);
            }
        } else if (rem >= ISTEP) {
#pragma unroll
            for (int u = 0; u < ISTEP; ++u) {
                step<HAS128>(A0, A1, A2, sch, kq, q[u]);
                if ((u & 3) == 3)
                    maybe_renorm<HAS128>(A0, A1, A2, e, sch, kq, skipf2);
            }
        } else {
            // GUARDED, fully unrolled: no dynamic q[] index, wave-uniform sel
#pragma unroll
            for (int u = 0; u < ISTEP; ++u) {
                const float A0o = A0, A1o = A1, A2o = A2;
                step<HAS128>(A0, A1, A2, sch, kq, q[u]);
                const bool v = u < rem;
                A0 = v ? A0 : A0o; A1 = v ? A1 : A1o;
                if (HAS128) A2 = v ? A2 : A2o;
                if ((u & 3) == 3)                  // value-preserving: no guard
                    maybe_renorm<HAS128>(A0, A1, A2, e, sch, kq, skipf2);
            }
        }
        __builtin_amdgcn_s_barrier();             // end of interval c
    }
    __builtin_amdgcn_s_barrier();                 // BF: lg ready
    const float lg = extra[2];
    const float ef = (float)e + lg + (float)(tend - 1);   // decay accounting
    const float l0 = LOG2(A0) + ef;
    const float l1 = LOG2(A1) + ef;
    const float a_prev = __shfl(l1, lab - 1);             // state 2*lab-1
    float a_last;
    if (HAS128) {
        const float l2 = LOG2(A2) + ef;
        a_last = __shfl(l2, 63);                          // state 128
    } else {
        a_last = __shfl(l0, lab);                         // state 2*lab
    }
    if (lane == 0) out[b] = -LN2F * lse2_2(a_last, a_prev);
}

__global__ __launch_bounds__(128) void ctc_fwd_kernel(
    const int* __restrict__ y_true, const float* __restrict__ y_pred,
    const int* __restrict__ input_len, const int* __restrict__ label_len,
    float* __restrict__ out)
{
    __shared__ __align__(16) float raw[2][ISTEP * C_];     // 64 KB
    __shared__ __align__(16) float qlb[2][64 * QSTR];      // 34.8 KB
    __shared__ float extra[4];          // [0]=A1init [1]=A0init [2]=lg

    const int b = blockIdx.x;
    const int tid = threadIdx.x;
    const int lane = tid & 63;
    const float* __restrict__ Pg = y_pred + (size_t)b * T_ * C_;
    const int label = y_true[b * L_ + lane];
    const int in_len = input_len[b];
    const int tend = in_len < T_ ? in_len : T_;            // >= 256
    const int nI = (tend + ISTEP - 1) / ISTEP;             // 4..8

    if (tid >= 64) {
        // ------------------------- producer (wave 1) -------------------------
        float llg = 0.0f;
        // stage intervals 0 and 1 (nI >= 4); 64 outstanding is fine, only
        // the wait immediate is capped (we use <= 32).
        stage_chunk(Pg, &raw[0][0], lane);
        stage_chunk(Pg + CHUNK * C_, &raw[0][CHUNK * C_], lane);
        stage_chunk(Pg + (size_t)ISTEP * C_, &raw[1][0], lane);
        stage_chunk(Pg + (size_t)(ISTEP + CHUNK) * C_, &raw[1][CHUNK * C_], lane);
        asm volatile("s_waitcnt vmcnt(32)" ::: "memory");  // interval 0 landed
        produce_chunk(&raw[0][0], &qlb[0][lane * QSTR], lane, label,
                      0, tend, llg);
        produce_chunk(&raw[0][CHUNK * C_], &qlb[0][lane * QSTR + CHUNK],
                      lane, label, CHUNK, tend, llg);
        if (lane == 0) {
            extra[0] = raw[0][label]  + EPSF;              // A1 init (s=1)
            extra[1] = raw[0][BLANK_] + EPSF;              // A0 init (s=0)
        }
        asm volatile("s_waitcnt lgkmcnt(0)" ::: "memory");
        __builtin_amdgcn_s_barrier();                      // P0
        for (int i = 0; i < nI; ++i) {
            const int js = i + 2, jp = i + 1;
            if (js < nI) {
                stage_chunk(Pg + (size_t)js * ISTEP * C_, &raw[js & 1][0], lane);
                stage_chunk(Pg + ((size_t)js * ISTEP + CHUNK) * C_,
                            &raw[js & 1][CHUNK * C_], lane);
            }
            if (jp < nI) {
                if (js < nI) asm volatile("s_waitcnt vmcnt(32)" ::: "memory");
                else         asm volatile("s_waitcnt vmcnt(0)" ::: "memory");
                produce_chunk(&raw[jp & 1][0], &qlb[jp & 1][lane * QSTR],
                              lane, label, jp * ISTEP, tend, llg);
                produce_chunk(&raw[jp & 1][CHUNK * C_],
                              &qlb[jp & 1][lane * QSTR + CHUNK],
                              lane, label, jp * ISTEP + CHUNK, tend, llg);
                asm volatile("s_waitcnt lgkmcnt(0)" ::: "memory");
            }
            __builtin_amdgcn_s_barrier();                  // end of interval i
        }
#pragma unroll
        for (int off = 16; off >= 1; off >>= 1) llg += __shfl_xor(llg, off);
        if (lane == 0) extra[2] = llg;                     // lg
        asm volatile("s_waitcnt lgkmcnt(0)" ::: "memory");
        __builtin_amdgcn_s_barrier();                      // BF
    } else {
        // ------------------------- consumer (wave 0) -------------------------
        const int lprev = __shfl_up(label, 1);
        const float skipf2 = (lane > 0 && label != lprev) ? 2.0f : 0.0f;
        const int lab = label_len[b];
        __builtin_amdgcn_s_barrier();                      // P0
        if (lab == L_)
            consumer_run<true >(qlb, extra, lane, lab, tend, nI, skipf2, out, b);
        else
            consumer_run<false>(qlb, extra, lane, lab, tend, nI, skipf2, out, b);
    }
}

extern "C" void kernel_launch(void* const* d_in, const int* in_sizes, int n_in,
                              void* d_out, int out_size, void* d_ws, size_t ws_size,
                              hipStream_t stream) {
    const int*   y_true    = (const int*)d_in[0];
    const float* y_pred    = (const float*)d_in[1];
    const int*   input_len = (const int*)d_in[2];
    const int*   label_len = (const int*)d_in[3];
    float* out = (float*)d_out;

    ctc_fwd_kernel<<<B_, 128, 0, stream>>>(y_true, y_pred, input_len, label_len, out);
}